// Round 4
// baseline (697.212 us; speedup 1.0000x reference)
//
#include <hip/hip_runtime.h>
#include <math.h>

#define SQ 4096
#define DM 1024
#define NB 4
#define MT (NB*SQ)   // 16384 flattened rows
#define XN ((size_t)MT*DM)

typedef __attribute__((ext_vector_type(4))) float f32x4;
typedef __attribute__((ext_vector_type(8))) short s16x8;

__device__ __forceinline__ unsigned short f2bf(float f) {
  union { float f; unsigned int u; } v; v.f = f;
  unsigned int u = v.u;
  u += 0x7fffu + ((u >> 16) & 1u);   // RNE
  return (unsigned short)(u >> 16);
}

__device__ __forceinline__ float bf2f(unsigned short u) {
  union { unsigned int i; float f; } v; v.i = ((unsigned int)u) << 16;
  return v.f;
}

__device__ __forceinline__ void async16(const void* g, void* l) {
  __builtin_amdgcn_global_load_lds(
      (const __attribute__((address_space(1))) unsigned int*)g,
      (__attribute__((address_space(3))) unsigned int*)l, 16, 0, 0);
}

// ---------------- fp32 -> bf16 convert, all 4 inputs in one dispatch ----------------
__global__ __launch_bounds__(256)
void cvt_all(const float* __restrict__ x, const float* __restrict__ Wq,
             const float* __restrict__ Wk, const float* __restrict__ Wv,
             unsigned short* __restrict__ xb, unsigned short* __restrict__ Wb) {
  size_t i = ((size_t)blockIdx.x * 256 + threadIdx.x) * 4;
  const float* src; unsigned short* dst;
  if (i < XN) { src = x + i; dst = xb + i; }
  else {
    size_t r = i - XN;
    int w = (int)(r >> 20);                 // DM*DM == 2^20
    size_t off = r & (((size_t)1 << 20) - 1);
    src = (w == 0 ? Wq : (w == 1 ? Wk : Wv)) + off;
    dst = Wb + r;
  }
  float4 f = *(const float4*)src;
  ushort4 o;
  o.x = f2bf(f.x); o.y = f2bf(f.y); o.z = f2bf(f.z); o.w = f2bf(f.w);
  *(ushort4*)dst = o;
}

// ---------------- shared m97-style 128x128xBK64 K-loop ----------------
// A[m][k] row-major stride LDA, B[n][k] row-major stride LDB, bf16.
template<int LDA, int LDB>
__device__ __forceinline__ void gemm_tile_body(
    const unsigned short* __restrict__ A, const unsigned short* __restrict__ B,
    unsigned short* As, unsigned short* Bs,
    int m0, int n0, int kext, f32x4 acc[4][4]) {
  const int tid = threadIdx.x, lane = tid & 63, wid = tid >> 6;
  const int quad = lane >> 4, l15 = lane & 15;
  const int wm = wid & 1, wn = wid >> 1;
  for (int k0 = 0; k0 < kext; k0 += 64) {
#pragma unroll
    for (int c = 0; c < 4; c++) {
      int slot = (wid * 4 + c) * 64 + lane;
      int r = slot >> 3;
      int kg = (slot & 7) ^ (r & 7);
      async16(A + (size_t)(m0 + r) * LDA + k0 + kg * 8, As + slot * 8);
      async16(B + (size_t)(n0 + r) * LDB + k0 + kg * 8, Bs + slot * 8);
    }
    asm volatile("s_waitcnt vmcnt(0)" ::: "memory");
    __syncthreads();
#pragma unroll
    for (int ks = 0; ks < 2; ks++) {
      s16x8 af[4], bfr[4];
#pragma unroll
      for (int t = 0; t < 4; t++) {
        int mr = wm * 64 + t * 16 + l15;
        af[t]  = *(const s16x8*)(As + mr * 64 + (((ks * 4 + quad) ^ (mr & 7)) * 8));
        int nr = wn * 64 + t * 16 + l15;
        bfr[t] = *(const s16x8*)(Bs + nr * 64 + (((ks * 4 + quad) ^ (nr & 7)) * 8));
      }
#pragma unroll
      for (int tm = 0; tm < 4; tm++)
#pragma unroll
        for (int tn = 0; tn < 4; tn++)
          acc[tm][tn] = __builtin_amdgcn_mfma_f32_16x16x32_bf16(af[tm], bfr[tn], acc[tm][tn], 0, 0, 0);
    }
    __syncthreads();
  }
}

// ---------------- merged QKV projection GEMM ----------------
// RoPE fused on Q/K epilogues; V epilogue transposes through LDS and writes
// Vt[b][d][s] directly (no separate transpose pass).
// 1-D grid 3072; xcd-swizzle: all 24 n-slabs of one m-tile share id%8 (same XCD)
// so the A(x) tile re-reads stay in one L2.
__global__ __launch_bounds__(256)
void qkv_gemm(const unsigned short* __restrict__ A,
              const unsigned short* __restrict__ Wb,
              unsigned short* __restrict__ QKV) {
  __shared__ unsigned short SM[2 * 128 * 64];
  unsigned short* As = SM;
  unsigned short* Bs = SM + 128 * 64;
  const int tid = threadIdx.x, lane = tid & 63, wid = tid >> 6;
  const int quad = lane >> 4, l15 = lane & 15;
  const int wm = wid & 1, wn = wid >> 1;

  const int id = blockIdx.x;
  const int xcd = id & 7, sgrp = id >> 3;
  const int n = sgrp % 24;
  const int m = (sgrp / 24) * 8 + xcd;
  const int mat = n >> 3;
  const int m0 = m * 128, n0 = (n & 7) * 128;

  f32x4 zero = {0.f, 0.f, 0.f, 0.f};
  f32x4 acc[4][4];
#pragma unroll
  for (int i = 0; i < 4; i++)
#pragma unroll
    for (int j = 0; j < 4; j++) acc[i][j] = zero;

  gemm_tile_body<DM, DM>(A, Wb + (size_t)mat * DM * DM, As, Bs, m0, n0, DM, acc);

  if (mat < 2) {
    // ---- Q/K epilogue: RoPE + bf16-pair pack ----
    unsigned short* C = QKV + (size_t)mat * XN;
    const bool ev = (lane & 1) == 0;
#pragma unroll
    for (int tm = 0; tm < 4; tm++) {
      int rowb = m0 + wm * 64 + tm * 16 + quad * 4;
#pragma unroll
      for (int tn = 0; tn < 4; tn++) {
        int col = n0 + wn * 64 + tn * 16 + l15;
        f32x4 v = acc[tm][tn];
        // inv_freq/(2pi); angle in revolutions, fract-reduced (v_sin range)
        float invr = exp2f(-(float)(col & ~1) * (13.287712379549449f / 1024.0f)) * 0.15915494309f;
#pragma unroll
        for (int g = 0; g < 4; g++) {
          int row = rowb + g;
          float rev = (float)(row & (SQ - 1)) * invr;
          rev -= floorf(rev);
          float sn, cs;
          __sincosf(rev * 6.283185307179586f, &sn, &cs);
          float part = __shfl_xor(v[g], 1);
          float e = ev ? v[g] : part;
          float o = ev ? part : v[g];
          float re = e * cs - o * sn;
          float ro = e * sn + o * cs;
          if (ev) {
            unsigned int pk = (unsigned int)f2bf(re) | ((unsigned int)f2bf(ro) << 16);
            *(unsigned int*)(C + (size_t)row * DM + col) = pk;
          }
        }
      }
    }
  } else {
    // ---- V epilogue: LDS-bounce transpose -> Vt[b][d][s] ----
    unsigned short* Vt = QKV + 2 * XN;
    const int b = m0 >> 12, s_in = m0 & (SQ - 1);
#pragma unroll
    for (int h = 0; h < 2; h++) {
      if (wn == h) {
#pragma unroll
        for (int tm = 0; tm < 4; tm++)
#pragma unroll
          for (int tn = 0; tn < 4; tn++) {
            int r = tn * 16 + l15;                      // d within half
            int c = wm * 64 + tm * 16 + quad * 4;       // s within tile
#pragma unroll
            for (int g = 0; g < 4; g++)
              SM[r * 136 + c + g] = f2bf(acc[tm][tn][g]);
          }
      }
      __syncthreads();
      {
        int r = tid >> 2, soff = (tid & 3) * 32;
        unsigned short* dstp = Vt + (size_t)b * DM * SQ +
                               (size_t)(n0 + h * 64 + r) * SQ + s_in + soff;
        const unsigned short* srcp = SM + r * 136 + soff;
#pragma unroll
        for (int k = 0; k < 4; k++)
          *(int4*)(dstp + k * 8) = *(const int4*)(srcp + k * 8);
      }
      __syncthreads();
    }
  }
}

// ---------------- pass1: S = Q K^T / 32, causal tiles only, bf16 out ----------------
// 1-D grid of 528*G blocks: b = bx % G, t = bx / G (triangular tile id, nt<=mt).
__global__ __launch_bounds__(256)
void qk_gemm(const unsigned short* __restrict__ Q, const unsigned short* __restrict__ K,
             unsigned short* __restrict__ S, int G) {
  __shared__ unsigned short As[128 * 64];
  __shared__ unsigned short Bs[128 * 64];
  const int lane = threadIdx.x & 63, wid = threadIdx.x >> 6;
  const int quad = lane >> 4, l15 = lane & 15;
  const int wm = wid & 1, wn = wid >> 1;

  const int b = blockIdx.x % G;
  int t = blockIdx.x / G;
  int mt = (int)((sqrtf(8.f * (float)t + 1.f) - 1.f) * 0.5f);
  while ((mt + 1) * (mt + 2) / 2 <= t) ++mt;
  while (mt * (mt + 1) / 2 > t) --mt;
  int nt = t - mt * (mt + 1) / 2;

  const unsigned short* Qg = Q + (size_t)b * SQ * DM;
  const unsigned short* Kg = K + (size_t)b * SQ * DM;
  unsigned short* Sg = S + (size_t)b * SQ * SQ;

  f32x4 zero = {0.f, 0.f, 0.f, 0.f};
  f32x4 acc[4][4];
#pragma unroll
  for (int i = 0; i < 4; i++)
#pragma unroll
    for (int j = 0; j < 4; j++) acc[i][j] = zero;

  gemm_tile_body<DM, DM>(Qg, Kg, As, Bs, mt * 128, nt * 128, DM, acc);

  const bool ev = (lane & 1) == 0;
#pragma unroll
  for (int tm = 0; tm < 4; tm++) {
    int rowb = mt * 128 + wm * 64 + tm * 16 + quad * 4;
#pragma unroll
    for (int tn = 0; tn < 4; tn++) {
      int col = nt * 128 + wn * 64 + tn * 16 + l15;
      f32x4 v = acc[tm][tn];
#pragma unroll
      for (int g = 0; g < 4; g++) {
        float sv = v[g] * 0.03125f;
        float part = __shfl_xor(sv, 1);
        if (ev) {
          unsigned int pk = (unsigned int)f2bf(sv) | ((unsigned int)f2bf(part) << 16);
          *(unsigned int*)(Sg + (size_t)(rowb + g) * SQ + col) = pk;
        }
      }
    }
  }
}

// ---------------- pass2: per-row softmax in place (bf16), store 1/l ----------------
__global__ __launch_bounds__(256)
void softmax_row(unsigned short* __restrict__ S, float* __restrict__ linv) {
  __shared__ int4 rowbuf4[512];   // 8 KB: entire row bf16
  __shared__ float redm[4], reds[4];
  unsigned short* rowbuf = (unsigned short*)rowbuf4;
  const int tid = threadIdx.x, lane = tid & 63, wid = tid >> 6;
  const int row = blockIdx.x;
  unsigned short* Srow = S + (size_t)blockIdx.y * SQ * SQ + (size_t)row * SQ;
  float* lg = linv + blockIdx.y * SQ;
  const int L = row + 1;
  const int nch = (L + 7) >> 3;                    // chunks holding causal data
  const int pch = ((((row >> 7) + 1) << 7)) >> 3;  // chunks to 128-aligned pad end

  float lmax = -INFINITY;
  for (int c = tid; c < nch; c += 256) {
    int4 v = *(const int4*)(Srow + (size_t)c * 8);
    rowbuf4[c] = v;
    const unsigned short* pe = (const unsigned short*)&v;
#pragma unroll
    for (int j = 0; j < 8; j++)
      if (c * 8 + j < L) lmax = fmaxf(lmax, bf2f(pe[j]));
  }
#pragma unroll
  for (int o = 32; o >= 1; o >>= 1) lmax = fmaxf(lmax, __shfl_xor(lmax, o));
  if (lane == 0) redm[wid] = lmax;
  __syncthreads();
  const float m = fmaxf(fmaxf(redm[0], redm[1]), fmaxf(redm[2], redm[3]));

  float lsum = 0.f;
  for (int c = tid; c < pch; c += 256) {
    union { int4 v; unsigned short s[8]; } o;
    if (c < nch) {
      const unsigned short* pe = rowbuf + c * 8;
#pragma unroll
      for (int j = 0; j < 8; j++) {
        float p = (c * 8 + j < L) ? __expf(bf2f(pe[j]) - m) : 0.f;
        lsum += p;
        o.s[j] = f2bf(p);
      }
    } else {
#pragma unroll
      for (int j = 0; j < 8; j++) o.s[j] = 0;
    }
    *(int4*)(Srow + (size_t)c * 8) = o.v;
  }
#pragma unroll
  for (int o = 32; o >= 1; o >>= 1) lsum += __shfl_xor(lsum, o);
  if (lane == 0) reds[wid] = lsum;
  __syncthreads();
  if (tid == 0) lg[row] = 1.0f / (reds[0] + reds[1] + reds[2] + reds[3]);
}

// ---------------- pass3: O = P @ V (Vt layout), scale 1/l, fp32 out ----------------
// 1-D grid of 256*G blocks: b = bx % G, t = bx / G; mt = 31-(t>>3) (longest-K first),
// nt = t&7. Note same-(nt,b) blocks share id%8 -> Vt-slab reuse stays in one XCD L2.
__global__ __launch_bounds__(256)
void pv_gemm(const unsigned short* __restrict__ P, const unsigned short* __restrict__ Vt,
             const float* __restrict__ linv, float* __restrict__ O, int G) {
  __shared__ unsigned short As[128 * 64];
  __shared__ unsigned short Bs[128 * 64];
  const int lane = threadIdx.x & 63, wid = threadIdx.x >> 6;
  const int quad = lane >> 4, l15 = lane & 15;
  const int wm = wid & 1, wn = wid >> 1;

  const int b = blockIdx.x % G;
  const int t = blockIdx.x / G;
  const int mt = 31 - (t >> 3);
  const int nt = t & 7;

  const unsigned short* Pg = P + (size_t)b * SQ * SQ;
  const unsigned short* Vg = Vt + (size_t)b * DM * SQ;
  const float* lg = linv + b * SQ;
  float* Og = O + (size_t)b * SQ * DM;

  f32x4 zero = {0.f, 0.f, 0.f, 0.f};
  f32x4 acc[4][4];
#pragma unroll
  for (int i = 0; i < 4; i++)
#pragma unroll
    for (int j = 0; j < 4; j++) acc[i][j] = zero;

  gemm_tile_body<SQ, SQ>(Pg, Vg, As, Bs, mt * 128, nt * 128, (mt + 1) * 128, acc);

  const bool ev = (lane & 1) == 0;
#pragma unroll
  for (int tm = 0; tm < 4; tm++) {
    int rowb = mt * 128 + wm * 64 + tm * 16 + quad * 4;
#pragma unroll
    for (int tn = 0; tn < 4; tn++) {
      int col = nt * 128 + wn * 64 + tn * 16 + l15;
      f32x4 v = acc[tm][tn];
#pragma unroll
      for (int g = 0; g < 4; g++) {
        float val = v[g] * lg[rowb + g];
        float part = __shfl_xor(val, 1);
        if (ev) {
          float2 st; st.x = val; st.y = part;
          *(float2*)(Og + (size_t)(rowb + g) * DM + col) = st;
        }
      }
    }
  }
}

extern "C" void kernel_launch(void* const* d_in, const int* in_sizes, int n_in,
                              void* d_out, int out_size, void* d_ws, size_t ws_size,
                              hipStream_t stream) {
  const float* x  = (const float*)d_in[0];
  const float* Wq = (const float*)d_in[1];
  const float* Wk = (const float*)d_in[2];
  const float* Wv = (const float*)d_in[3];
  float* out = (float*)d_out;

  // workspace layout (bf16 elems unless noted)
  unsigned short* xb  = (unsigned short*)d_ws;
  unsigned short* Wb  = xb + XN;                         // [3][DM][DM]
  unsigned short* Qb  = Wb + (size_t)3 * DM * DM;        // Q [NB][SQ][DM]
  unsigned short* Kb  = Qb + XN;                         // K [NB][SQ][DM]
  unsigned short* Vtb = Kb + XN;                         // Vt [NB][DM][SQ]
  unsigned short* Sb  = Vtb + XN;                        // G batches of S/P

  // choose largest batch group that fits the workspace (ws_size constant
  // across calls -> identical launches every call, graph-capture safe)
  const size_t base_bytes = (XN + 3 * (size_t)DM * DM + 3 * XN) * 2;
  int G = 1;
  for (int g = 4; g >= 1; g >>= 1) {
    size_t need = base_bytes + (size_t)g * SQ * SQ * 2 + (size_t)g * SQ * 4;
    if (ws_size >= need) { G = g; break; }
  }
  float* linv = (float*)(Sb + (size_t)G * SQ * SQ);

  cvt_all<<<(int)((XN + 3 * (size_t)DM * DM) / 1024), 256, 0, stream>>>(
      x, Wq, Wk, Wv, xb, Wb);

  qkv_gemm<<<3072, 256, 0, stream>>>(xb, Wb, Qb);

  for (int g = 0; g < NB; g += G) {
    qk_gemm<<<528 * G, 256, 0, stream>>>(
        Qb + (size_t)g * SQ * DM, Kb + (size_t)g * SQ * DM, Sb, G);
    softmax_row<<<dim3(SQ, G), 256, 0, stream>>>(Sb, linv);
    pv_gemm<<<256 * G, 256, 0, stream>>>(
        Sb, Vtb + (size_t)g * DM * SQ, linv, out + (size_t)g * SQ * DM, G);
  }
}

// Round 5
// 531.750 us; speedup vs baseline: 1.3112x; 1.3112x over previous
//
#include <hip/hip_runtime.h>
#include <math.h>

#define SQ 4096
#define DM 1024
#define NB 4
#define MT (NB*SQ)   // 16384 flattened rows
#define XN ((size_t)MT*DM)

typedef __attribute__((ext_vector_type(4))) float f32x4;
typedef __attribute__((ext_vector_type(8))) short s16x8;

__device__ __forceinline__ unsigned short f2bf(float f) {
  union { float f; unsigned int u; } v; v.f = f;
  unsigned int u = v.u;
  u += 0x7fffu + ((u >> 16) & 1u);   // RNE
  return (unsigned short)(u >> 16);
}

__device__ __forceinline__ float bf2f(unsigned short u) {
  union { unsigned int i; float f; } v; v.i = ((unsigned int)u) << 16;
  return v.f;
}

__device__ __forceinline__ void async16(const void* g, void* l) {
  __builtin_amdgcn_global_load_lds(
      (const __attribute__((address_space(1))) unsigned int*)g,
      (__attribute__((address_space(3))) unsigned int*)l, 16, 0, 0);
}

// ---------------- fp32 -> bf16 convert, all 4 inputs in one dispatch ----------------
__global__ __launch_bounds__(256)
void cvt_all(const float* __restrict__ x, const float* __restrict__ Wq,
             const float* __restrict__ Wk, const float* __restrict__ Wv,
             unsigned short* __restrict__ xb, unsigned short* __restrict__ Wb) {
  size_t i = ((size_t)blockIdx.x * 256 + threadIdx.x) * 4;
  const float* src; unsigned short* dst;
  if (i < XN) { src = x + i; dst = xb + i; }
  else {
    size_t r = i - XN;
    int w = (int)(r >> 20);                 // DM*DM == 2^20
    size_t off = r & (((size_t)1 << 20) - 1);
    src = (w == 0 ? Wq : (w == 1 ? Wk : Wv)) + off;
    dst = Wb + r;
  }
  float4 f = *(const float4*)src;
  ushort4 o;
  o.x = f2bf(f.x); o.y = f2bf(f.y); o.z = f2bf(f.z); o.w = f2bf(f.w);
  *(ushort4*)dst = o;
}

// ---------------- shared m97-style 128x128xBK64 K-loop, hoisted addressing ----------------
// A[m][k] stride LDA, B[n][k] stride LDB, bf16.
// Index algebra (equiv. to r3 form, verified):
//   stage: slot=(wid*4+c)*64+lane -> r = wid*32 + (lane>>3) + 8c ; kg = (lane&7)^(lane>>3)
//          (c-invariant!), LDS slot*8 = (wid*256+lane)*8 + c*512
//   frags: off = (w*64+l15)*64 + (quad^(l15&7))*8, then ^(ks*32), + t*1024
//          (bit-disjoint: row bits>=6, xor-term bits 3..5, t term bits>=10)
template<int LDA, int LDB>
__device__ __forceinline__ void gemm_tile_body(
    const unsigned short* __restrict__ A, const unsigned short* __restrict__ B,
    unsigned short* As, unsigned short* Bs,
    int m0, int n0, int kext, f32x4 acc[4][4]) {
  const int tid = threadIdx.x, lane = tid & 63, wid = tid >> 6;
  const int quad = lane >> 4, l15 = lane & 15;
  const int wm = wid & 1, wn = wid >> 1;

  const int rbase = wid * 32 + (lane >> 3);
  const int kg8   = ((lane & 7) ^ (lane >> 3)) * 8;
  const unsigned short* Ab = A + (size_t)(m0 + rbase) * LDA + kg8;
  const unsigned short* Bb = B + (size_t)(n0 + rbase) * LDB + kg8;
  unsigned short* Asl = As + (wid * 256 + lane) * 8;
  unsigned short* Bsl = Bs + (wid * 256 + lane) * 8;
  const int xorq = (quad ^ (l15 & 7)) * 8;
  const int am = (wm * 64 + l15) * 64 + xorq;
  const int bn = (wn * 64 + l15) * 64 + xorq;

  for (int k0 = 0; k0 < kext; k0 += 64) {
#pragma unroll
    for (int c = 0; c < 4; c++) {
      async16(Ab + (size_t)c * 8 * LDA + k0, Asl + c * 512);
      async16(Bb + (size_t)c * 8 * LDB + k0, Bsl + c * 512);
    }
    asm volatile("s_waitcnt vmcnt(0)" ::: "memory");
    __syncthreads();
#pragma unroll
    for (int ks = 0; ks < 2; ks++) {
      const int ax = am ^ (ks * 32), bx = bn ^ (ks * 32);
      s16x8 af[4], bfr[4];
#pragma unroll
      for (int t = 0; t < 4; t++) {
        af[t]  = *(const s16x8*)(As + ax + t * 1024);
        bfr[t] = *(const s16x8*)(Bs + bx + t * 1024);
      }
#pragma unroll
      for (int tm = 0; tm < 4; tm++)
#pragma unroll
        for (int tn = 0; tn < 4; tn++)
          acc[tm][tn] = __builtin_amdgcn_mfma_f32_16x16x32_bf16(af[tm], bfr[tn], acc[tm][tn], 0, 0, 0);
    }
    __syncthreads();
  }
}

// ---------------- QKV projection GEMM, compile-time ROPE split ----------------
// ROPE=1: grid (128,16), mat = by>>3 in {Q,K}. ROPE=0: grid (128,8), mat = V.
// 2-D grid default order (x fastest): consecutive blocks share the W slab (r3-proven
// L2 pattern; the r4 %8 swizzle REGRESSED FETCH 136->323 MB — do not reintroduce).
template<int ROPE>
__global__ __launch_bounds__(256, 3)
void proj_gemm(const unsigned short* __restrict__ A,
               const unsigned short* __restrict__ Wb,
               unsigned short* __restrict__ QKV) {
  __shared__ unsigned short As[128 * 64];
  __shared__ unsigned short Bs[128 * 64];
  const int lane = threadIdx.x & 63, wid = threadIdx.x >> 6;
  const int quad = lane >> 4, l15 = lane & 15;
  const int wm = wid & 1, wn = wid >> 1;
  const int mat = ROPE ? (blockIdx.y >> 3) : 2;
  const int m0 = blockIdx.x * 128, n0 = (blockIdx.y & 7) * 128;

  f32x4 zero = {0.f, 0.f, 0.f, 0.f};
  f32x4 acc[4][4];
#pragma unroll
  for (int i = 0; i < 4; i++)
#pragma unroll
    for (int j = 0; j < 4; j++) acc[i][j] = zero;

  gemm_tile_body<DM, DM>(A, Wb + (size_t)mat * DM * DM, As, Bs, m0, n0, DM, acc);

  unsigned short* C = QKV + (size_t)mat * XN;
  const bool ev = (lane & 1) == 0;
#pragma unroll
  for (int tm = 0; tm < 4; tm++) {
    int rowb = m0 + wm * 64 + tm * 16 + quad * 4;
#pragma unroll
    for (int tn = 0; tn < 4; tn++) {
      int col = n0 + wn * 64 + tn * 16 + l15;
      f32x4 v = acc[tm][tn];
      if (ROPE) {
        // inv_freq/(2pi); angle in revolutions, fract-reduced (v_sin range)
        float invr = exp2f(-(float)(col & ~1) * (13.287712379549449f / 1024.0f)) * 0.15915494309f;
#pragma unroll
        for (int g = 0; g < 4; g++) {
          int row = rowb + g;
          float rev = (float)(row & (SQ - 1)) * invr;
          rev -= floorf(rev);
          float sn, cs;
          __sincosf(rev * 6.283185307179586f, &sn, &cs);
          float part = __shfl_xor(v[g], 1);
          float e = ev ? v[g] : part;
          float o = ev ? part : v[g];
          float re = e * cs - o * sn;
          float ro = e * sn + o * cs;
          if (ev) {
            unsigned int pk = (unsigned int)f2bf(re) | ((unsigned int)f2bf(ro) << 16);
            *(unsigned int*)(C + (size_t)row * DM + col) = pk;
          }
        }
      } else {
#pragma unroll
        for (int g = 0; g < 4; g++) {
          int row = rowb + g;
          float part = __shfl_xor(v[g], 1);
          if (ev) {
            unsigned int pk = (unsigned int)f2bf(v[g]) | ((unsigned int)f2bf(part) << 16);
            *(unsigned int*)(C + (size_t)row * DM + col) = pk;
          }
        }
      }
    }
  }
}

// ---------------- V [b][s][d] -> Vt [b][d][s] ----------------
__global__ __launch_bounds__(256)
void transpose_k(const unsigned short* __restrict__ V, unsigned short* __restrict__ Vt) {
  const int b = blockIdx.y;
  const int s0 = blockIdx.x * 64;
  const int lane = threadIdx.x & 63, w = threadIdx.x >> 6;
  const unsigned short* Vb = V + (size_t)b * SQ * DM;
  unsigned short* Vtb = Vt + (size_t)b * DM * SQ;
  const int s = s0 + lane;
#pragma unroll 4
  for (int i = 0; i < 32; i++) {
    int d = (w * 32 + i) * 8;
    int4 v = *(const int4*)(Vb + (size_t)s * DM + d);
    const unsigned short* pv = (const unsigned short*)&v;
#pragma unroll
    for (int j = 0; j < 8; j++)
      Vtb[(size_t)(d + j) * SQ + s] = pv[j];
  }
}

// ---------------- pass1: S = Q K^T / 32, causal tiles only, bf16 out ----------------
// 1-D grid of 528*G blocks: b = bx % G, t = bx / G (triangular tile id, nt<=mt).
__global__ __launch_bounds__(256, 3)
void qk_gemm(const unsigned short* __restrict__ Q, const unsigned short* __restrict__ K,
             unsigned short* __restrict__ S, int G) {
  __shared__ unsigned short As[128 * 64];
  __shared__ unsigned short Bs[128 * 64];
  const int lane = threadIdx.x & 63, wid = threadIdx.x >> 6;
  const int quad = lane >> 4, l15 = lane & 15;
  const int wm = wid & 1, wn = wid >> 1;

  const int b = blockIdx.x % G;
  int t = blockIdx.x / G;
  int mt = (int)((sqrtf(8.f * (float)t + 1.f) - 1.f) * 0.5f);
  while ((mt + 1) * (mt + 2) / 2 <= t) ++mt;
  while (mt * (mt + 1) / 2 > t) --mt;
  int nt = t - mt * (mt + 1) / 2;

  const unsigned short* Qg = Q + (size_t)b * SQ * DM;
  const unsigned short* Kg = K + (size_t)b * SQ * DM;
  unsigned short* Sg = S + (size_t)b * SQ * SQ;

  f32x4 zero = {0.f, 0.f, 0.f, 0.f};
  f32x4 acc[4][4];
#pragma unroll
  for (int i = 0; i < 4; i++)
#pragma unroll
    for (int j = 0; j < 4; j++) acc[i][j] = zero;

  gemm_tile_body<DM, DM>(Qg, Kg, As, Bs, mt * 128, nt * 128, DM, acc);

  const bool ev = (lane & 1) == 0;
#pragma unroll
  for (int tm = 0; tm < 4; tm++) {
    int rowb = mt * 128 + wm * 64 + tm * 16 + quad * 4;
#pragma unroll
    for (int tn = 0; tn < 4; tn++) {
      int col = nt * 128 + wn * 64 + tn * 16 + l15;
      f32x4 v = acc[tm][tn];
#pragma unroll
      for (int g = 0; g < 4; g++) {
        float sv = v[g] * 0.03125f;
        float part = __shfl_xor(sv, 1);
        if (ev) {
          unsigned int pk = (unsigned int)f2bf(sv) | ((unsigned int)f2bf(part) << 16);
          *(unsigned int*)(Sg + (size_t)(rowb + g) * SQ + col) = pk;
        }
      }
    }
  }
}

// ---------------- pass2: per-row softmax in place (bf16), store 1/l ----------------
__global__ __launch_bounds__(256)
void softmax_row(unsigned short* __restrict__ S, float* __restrict__ linv) {
  __shared__ int4 rowbuf4[512];   // 8 KB: entire row bf16
  __shared__ float redm[4], reds[4];
  unsigned short* rowbuf = (unsigned short*)rowbuf4;
  const int tid = threadIdx.x, lane = tid & 63, wid = tid >> 6;
  const int row = blockIdx.x;
  unsigned short* Srow = S + (size_t)blockIdx.y * SQ * SQ + (size_t)row * SQ;
  float* lg = linv + blockIdx.y * SQ;
  const int L = row + 1;
  const int nch = (L + 7) >> 3;                    // chunks holding causal data
  const int pch = ((((row >> 7) + 1) << 7)) >> 3;  // chunks to 128-aligned pad end

  float lmax = -INFINITY;
  for (int c = tid; c < nch; c += 256) {
    int4 v = *(const int4*)(Srow + (size_t)c * 8);
    rowbuf4[c] = v;
    const unsigned short* pe = (const unsigned short*)&v;
#pragma unroll
    for (int j = 0; j < 8; j++)
      if (c * 8 + j < L) lmax = fmaxf(lmax, bf2f(pe[j]));
  }
#pragma unroll
  for (int o = 32; o >= 1; o >>= 1) lmax = fmaxf(lmax, __shfl_xor(lmax, o));
  if (lane == 0) redm[wid] = lmax;
  __syncthreads();
  const float m = fmaxf(fmaxf(redm[0], redm[1]), fmaxf(redm[2], redm[3]));

  float lsum = 0.f;
  for (int c = tid; c < pch; c += 256) {
    union { int4 v; unsigned short s[8]; } o;
    if (c < nch) {
      const unsigned short* pe = rowbuf + c * 8;
#pragma unroll
      for (int j = 0; j < 8; j++) {
        float p = (c * 8 + j < L) ? __expf(bf2f(pe[j]) - m) : 0.f;
        lsum += p;
        o.s[j] = f2bf(p);
      }
    } else {
#pragma unroll
      for (int j = 0; j < 8; j++) o.s[j] = 0;
    }
    *(int4*)(Srow + (size_t)c * 8) = o.v;
  }
#pragma unroll
  for (int o = 32; o >= 1; o >>= 1) lsum += __shfl_xor(lsum, o);
  if (lane == 0) reds[wid] = lsum;
  __syncthreads();
  if (tid == 0) lg[row] = 1.0f / (reds[0] + reds[1] + reds[2] + reds[3]);
}

// ---------------- pass3: O = P @ V (Vt layout), scale 1/l, fp32 out ----------------
// 1-D grid of 256*G blocks: b = bx % G, t = bx / G; mt = 31-(t>>3) (longest-K first),
// nt = t&7.
__global__ __launch_bounds__(256, 3)
void pv_gemm(const unsigned short* __restrict__ P, const unsigned short* __restrict__ Vt,
             const float* __restrict__ linv, float* __restrict__ O, int G) {
  __shared__ unsigned short As[128 * 64];
  __shared__ unsigned short Bs[128 * 64];
  const int lane = threadIdx.x & 63, wid = threadIdx.x >> 6;
  const int quad = lane >> 4, l15 = lane & 15;
  const int wm = wid & 1, wn = wid >> 1;

  const int b = blockIdx.x % G;
  const int t = blockIdx.x / G;
  const int mt = 31 - (t >> 3);
  const int nt = t & 7;

  const unsigned short* Pg = P + (size_t)b * SQ * SQ;
  const unsigned short* Vg = Vt + (size_t)b * DM * SQ;
  const float* lg = linv + b * SQ;
  float* Og = O + (size_t)b * SQ * DM;

  f32x4 zero = {0.f, 0.f, 0.f, 0.f};
  f32x4 acc[4][4];
#pragma unroll
  for (int i = 0; i < 4; i++)
#pragma unroll
    for (int j = 0; j < 4; j++) acc[i][j] = zero;

  gemm_tile_body<SQ, SQ>(Pg, Vg, As, Bs, mt * 128, nt * 128, (mt + 1) * 128, acc);

  const bool ev = (lane & 1) == 0;
#pragma unroll
  for (int tm = 0; tm < 4; tm++) {
    int rowb = mt * 128 + wm * 64 + tm * 16 + quad * 4;
#pragma unroll
    for (int tn = 0; tn < 4; tn++) {
      int col = nt * 128 + wn * 64 + tn * 16 + l15;
      f32x4 v = acc[tm][tn];
#pragma unroll
      for (int g = 0; g < 4; g++) {
        float val = v[g] * lg[rowb + g];
        float part = __shfl_xor(val, 1);
        if (ev) {
          float2 st; st.x = val; st.y = part;
          *(float2*)(Og + (size_t)(rowb + g) * DM + col) = st;
        }
      }
    }
  }
}

extern "C" void kernel_launch(void* const* d_in, const int* in_sizes, int n_in,
                              void* d_out, int out_size, void* d_ws, size_t ws_size,
                              hipStream_t stream) {
  const float* x  = (const float*)d_in[0];
  const float* Wq = (const float*)d_in[1];
  const float* Wk = (const float*)d_in[2];
  const float* Wv = (const float*)d_in[3];
  float* out = (float*)d_out;

  // workspace layout (bf16 elems unless noted); Vt aliases xb (dead after proj)
  unsigned short* xb  = (unsigned short*)d_ws;
  unsigned short* Wb  = xb + XN;                         // [3][DM][DM]
  unsigned short* Qb  = Wb + (size_t)3 * DM * DM;        // [3][MT][DM] = Q,K,V
  unsigned short* Kb  = Qb + XN;
  unsigned short* Vb  = Kb + XN;
  unsigned short* Sb  = Vb + XN;                         // G batches of S/P
  unsigned short* Vtb = xb;   // alias

  // choose largest batch group that fits the workspace (ws_size constant
  // across calls -> identical launches every call, graph-capture safe)
  const size_t base_bytes = (XN + 3 * (size_t)DM * DM + 3 * XN) * 2;
  int G = 1;
  for (int g = 4; g >= 1; g >>= 1) {
    size_t need = base_bytes + (size_t)g * SQ * SQ * 2 + (size_t)g * SQ * 4;
    if (ws_size >= need) { G = g; break; }
  }
  float* linv = (float*)(Sb + (size_t)G * SQ * SQ);

  cvt_all<<<(int)((XN + 3 * (size_t)DM * DM) / 1024), 256, 0, stream>>>(
      x, Wq, Wk, Wv, xb, Wb);

  proj_gemm<1><<<dim3(MT / 128, 16), 256, 0, stream>>>(xb, Wb, Qb);
  proj_gemm<0><<<dim3(MT / 128, 8), 256, 0, stream>>>(xb, Wb, Qb);

  transpose_k<<<dim3(SQ / 64, NB), 256, 0, stream>>>(Vb, Vtb);

  for (int g = 0; g < NB; g += G) {
    qk_gemm<<<528 * G, 256, 0, stream>>>(
        Qb + (size_t)g * SQ * DM, Kb + (size_t)g * SQ * DM, Sb, G);
    softmax_row<<<dim3(SQ, G), 256, 0, stream>>>(Sb, linv);
    pv_gemm<<<256 * G, 256, 0, stream>>>(
        Sb, Vtb + (size_t)g * DM * SQ, linv, out + (size_t)g * SQ * DM, G);
  }
}